// Round 1
// baseline (136.797 us; speedup 1.0000x reference)
//
#include <hip/hip_runtime.h>
#include <math.h>

#ifndef M_PI
#define M_PI 3.14159265358979323846
#endif

constexpr int BLOCK = 256;   // threads per block (i-points per block)
constexpr int TILE  = 512;   // j-points staged in LDS per iteration
constexpr int SPLIT = 16;    // j-dimension slices (blockIdx.y)

// y[i,c] = norms[c] * sum_j exp(-(a[j] + b[i,c]) * ||xi-xj||^2) * f[j]
// with b[i,:] = {a[i]/2, a[i], 2a[i]}  (since B0=B2, C0=C2 when A=D=2)
// => with u = exp2(-(a_i*log2e/2)*s), A = exp2(-(a_j*log2e)*s):
//    w1 = A*u, w2 = A*u^2, w3 = A*u^4
__global__ __launch_bounds__(BLOCK)
void cider_kernel(const float* __restrict__ rho,
                  const float* __restrict__ gamma,
                  const float* __restrict__ coords,
                  const float* __restrict__ weights,
                  float* __restrict__ out,
                  int n, float C2, float Kttf,
                  float n1, float n2, float n3)
{
    __shared__ float4 sp[TILE];  // x, y, z, a2j (= a_j * log2e)
    __shared__ float  sf[TILE];  // f_j = weights_j * rho_j

    const float LOG2E = 1.4426950408889634f;
    const float PI_F  = 3.14159265358979f;

    const int i      = blockIdx.x * BLOCK + threadIdx.x;
    const int jcount = n / SPLIT;
    const int j0     = blockIdx.y * jcount;

    // per-i parameters
    float r   = rho[i] + 1e-8f;
    float sc  = PI_F * powf(0.5f * r, 2.0f / 3.0f);
    float xq  = (gamma[i] / (8.0f * r)) / (Kttf * powf(r, 5.0f / 3.0f));
    float a_i = sc * (2.0f + C2 * xq);
    float m2  = 0.5f * LOG2E * a_i;          // b1 * log2e
    float xi = coords[3*i+0], yi = coords[3*i+1], zi = coords[3*i+2];

    float acc1 = 0.f, acc2 = 0.f, acc3 = 0.f;

    for (int tb = 0; tb < jcount; tb += TILE) {
        __syncthreads();
        for (int t = threadIdx.x; t < TILE; t += BLOCK) {
            int   j   = j0 + tb + t;
            float rj  = rho[j] + 1e-8f;
            float scj = PI_F * powf(0.5f * rj, 2.0f / 3.0f);
            float xj  = (gamma[j] / (8.0f * rj)) / (Kttf * powf(rj, 5.0f / 3.0f));
            float a2j = LOG2E * scj * (2.0f + C2 * xj);
            sp[t] = make_float4(coords[3*j+0], coords[3*j+1], coords[3*j+2], a2j);
            sf[t] = weights[j] * rho[j];
        }
        __syncthreads();

        #pragma unroll 8
        for (int t = 0; t < TILE; ++t) {
            float4 p  = sp[t];
            float  dx = xi - p.x, dy = yi - p.y, dz = zi - p.z;
            float  s  = fmaf(dx, dx, fmaf(dy, dy, dz * dz));
            float  A  = __builtin_amdgcn_exp2f(-p.w * s);
            float  u  = __builtin_amdgcn_exp2f(-m2 * s);
            float  u2 = u * u;
            float  u4 = u2 * u2;
            float  t0 = A * sf[t];
            acc1 = fmaf(t0, u,  acc1);
            acc2 = fmaf(t0, u2, acc2);
            acc3 = fmaf(t0, u4, acc3);
        }
    }

    atomicAdd(&out[3*i+0], acc1 * n1);
    atomicAdd(&out[3*i+1], acc2 * n2);
    atomicAdd(&out[3*i+2], acc3 * n3);
}

extern "C" void kernel_launch(void* const* d_in, const int* in_sizes, int n_in,
                              void* d_out, int out_size, void* d_ws, size_t ws_size,
                              hipStream_t stream)
{
    const float* rho     = (const float*)d_in[0];
    const float* gamma   = (const float*)d_in[1];
    const float* coords  = (const float*)d_in[2];
    const float* weights = (const float*)d_in[3];
    float*       out     = (float*)d_out;
    const int    n       = in_sizes[0];

    // host-side constants in double precision
    const double C2d  = pow(6.0 * M_PI * M_PI, 2.0 / 3.0) * (6.0 * 2.0 / (160.0 * M_PI));
    const double Kd   = 0.3 * pow(3.0 * M_PI * M_PI, 2.0 / 3.0);
    const float  nrm1 = (float)pow(1.5, 1.5);
    const float  nrm2 = (float)pow(2.0, 1.5);
    const float  nrm3 = (float)pow(3.0, 1.5);

    hipMemsetAsync(out, 0, (size_t)out_size * sizeof(float), stream);

    dim3 grid(n / BLOCK, SPLIT);
    cider_kernel<<<grid, BLOCK, 0, stream>>>(rho, gamma, coords, weights, out,
                                             n, (float)C2d, (float)Kd,
                                             nrm1, nrm2, nrm3);
}

// Round 2
// 103.128 us; speedup vs baseline: 1.3265x; 1.3265x over previous
//
#include <hip/hip_runtime.h>
#include <math.h>

#ifndef M_PI
#define M_PI 3.14159265358979323846
#endif

typedef float v2f __attribute__((ext_vector_type(2)));

constexpr int BLOCK = 256;   // threads per block (i-points per block)
constexpr int SPLIT = 32;    // j-dimension slices (blockIdx.y)

// y[i,c] = norms[c] * sum_j exp(-(a[j] + b[i,c]) * ||xi-xj||^2) * f[j]
// b[i,:] = {a[i]/2, a[i], 2a[i]}  (B0=B2, C0=C2 when A=D=2)
// With u = exp2(-(a_i/2*log2e)*s), A = exp2(-(a_j*log2e)*s):
//   w1 = A*u, w2 = A*u^2, w3 = A*u^4

// Precompute per-point SoA arrays in d_ws so the main kernel's j-loop reads
// are wave-uniform scalar loads (s_load), freeing the VALU/LDS pipes.
__global__ __launch_bounds__(256)
void cider_pre(const float* __restrict__ rho,
               const float* __restrict__ gamma,
               const float* __restrict__ coords,
               const float* __restrict__ weights,
               float* __restrict__ X, float* __restrict__ Y,
               float* __restrict__ Z, float* __restrict__ A2,
               float* __restrict__ F,
               int n, float C2, float Kttf)
{
    int j = blockIdx.x * 256 + threadIdx.x;
    if (j >= n) return;
    const float LOG2E = 1.4426950408889634f;
    const float PI_F  = 3.14159265358979f;
    float r   = rho[j] + 1e-8f;
    float sc  = PI_F * powf(0.5f * r, 2.0f / 3.0f);
    float xq  = (gamma[j] / (8.0f * r)) / (Kttf * powf(r, 5.0f / 3.0f));
    A2[j] = LOG2E * sc * (2.0f + C2 * xq);   // a_j * log2(e)
    X[j]  = coords[3*j+0];
    Y[j]  = coords[3*j+1];
    Z[j]  = coords[3*j+2];
    F[j]  = weights[j] * rho[j];
}

__global__ __launch_bounds__(BLOCK)
void cider_main(const float* __restrict__ X, const float* __restrict__ Y,
                const float* __restrict__ Z, const float* __restrict__ A2,
                const float* __restrict__ F, float* __restrict__ out,
                int n, float n1, float n2, float n3)
{
    const int i      = blockIdx.x * BLOCK + threadIdx.x;
    const int jcount = n / SPLIT;
    const int j0     = blockIdx.y * jcount;

    const float xi = X[i], yi = Y[i], zi = Z[i];
    const float m2 = 0.5f * A2[i];          // (a_i/2) * log2(e)

    // wave-uniform j-pointers (j0 even, arrays 8B-aligned) -> scalar loads
    const v2f* __restrict__ Xv = (const v2f*)(X  + j0);
    const v2f* __restrict__ Yv = (const v2f*)(Y  + j0);
    const v2f* __restrict__ Zv = (const v2f*)(Z  + j0);
    const v2f* __restrict__ Av = (const v2f*)(A2 + j0);
    const v2f* __restrict__ Fv = (const v2f*)(F  + j0);

    v2f acc1 = {0.f, 0.f}, acc2 = {0.f, 0.f}, acc3 = {0.f, 0.f};

    const int nt = jcount / 2;
    #pragma unroll 4
    for (int t = 0; t < nt; ++t) {
        v2f dx = Xv[t] - xi;
        v2f dy = Yv[t] - yi;
        v2f dz = Zv[t] - zi;
        v2f s  = dx * dx + dy * dy + dz * dz;   // contracts to v_pk_fma
        v2f argA = -(Av[t] * s);
        v2f argU = -(m2 * s);
        v2f A, u;
        A.x = __builtin_amdgcn_exp2f(argA.x);
        A.y = __builtin_amdgcn_exp2f(argA.y);
        u.x = __builtin_amdgcn_exp2f(argU.x);
        u.y = __builtin_amdgcn_exp2f(argU.y);
        v2f u2 = u * u;
        v2f u4 = u2 * u2;
        v2f t0 = A * Fv[t];
        acc1 += t0 * u;
        acc2 += t0 * u2;
        acc3 += t0 * u4;
    }

    atomicAdd(&out[3*i+0], (acc1.x + acc1.y) * n1);
    atomicAdd(&out[3*i+1], (acc2.x + acc2.y) * n2);
    atomicAdd(&out[3*i+2], (acc3.x + acc3.y) * n3);
}

extern "C" void kernel_launch(void* const* d_in, const int* in_sizes, int n_in,
                              void* d_out, int out_size, void* d_ws, size_t ws_size,
                              hipStream_t stream)
{
    const float* rho     = (const float*)d_in[0];
    const float* gamma   = (const float*)d_in[1];
    const float* coords  = (const float*)d_in[2];
    const float* weights = (const float*)d_in[3];
    float*       out     = (float*)d_out;
    const int    n       = in_sizes[0];

    const double C2d  = pow(6.0 * M_PI * M_PI, 2.0 / 3.0) * (6.0 * 2.0 / (160.0 * M_PI));
    const double Kd   = 0.3 * pow(3.0 * M_PI * M_PI, 2.0 / 3.0);
    const float  nrm1 = (float)pow(1.5, 1.5);
    const float  nrm2 = (float)pow(2.0, 1.5);
    const float  nrm3 = (float)pow(3.0, 1.5);

    float* X  = (float*)d_ws;
    float* Y  = X + n;
    float* Z  = Y + n;
    float* A2 = Z + n;
    float* F  = A2 + n;

    cider_pre<<<(n + 255) / 256, 256, 0, stream>>>(rho, gamma, coords, weights,
                                                   X, Y, Z, A2, F,
                                                   n, (float)C2d, (float)Kd);

    hipMemsetAsync(out, 0, (size_t)out_size * sizeof(float), stream);

    dim3 grid(n / BLOCK, SPLIT);
    cider_main<<<grid, BLOCK, 0, stream>>>(X, Y, Z, A2, F, out,
                                           n, nrm1, nrm2, nrm3);
}